// Round 11
// baseline (569.213 us; speedup 1.0000x reference)
//
#include <hip/hip_runtime.h>
#include <math.h>

// Problem constants (fixed by setup_inputs)
#define Bz 8
#define Tz 1024
#define Dz 512
#define FFz 2048
#define Hz 8
#define DHz 64
#define Mz (Bz * Tz)  // 8192 rows

typedef __attribute__((ext_vector_type(8))) short short8;   // 8 bf16 (4 VGPRs)
typedef __attribute__((ext_vector_type(4))) float f32x4;    // MFMA accumulator

__device__ inline unsigned short f2bf(float f) {  // RNE fp32 -> bf16
  unsigned u = __builtin_bit_cast(unsigned, f);
  return (unsigned short)((u + 0x7FFFu + ((u >> 16) & 1u)) >> 16);
}
__device__ inline float bf2f(unsigned short h) {
  unsigned u = (unsigned)h << 16;
  return __builtin_bit_cast(float, u);
}

// Async global->LDS 16B: LDS dest = wave-uniform base + lane*16 (HW rule),
// global src is per-lane. __syncthreads() drains vmcnt before s_barrier.
__device__ inline void gll16(const unsigned short* g, unsigned short* l) {
  __builtin_amdgcn_global_load_lds(
      (const __attribute__((address_space(1))) void*)g,
      (__attribute__((address_space(3))) void*)l, 16, 0, 0);
}

// XCD-aware decode for the 1024-block attention grids (8 XCDs round-robin by
// blockIdx). g = xcd + 8*(qt + 16*bhi), bh = bhi*8 + xcd.
__device__ inline void attn_decode(int g, int& b, int& h, int& qt) {
  const int xcd = g & 7;
  const int j = g >> 3;
  qt = j & 15;
  const int bh = ((j >> 4) << 3) | xcd;
  b = bh >> 3;
  h = bh & 7;
}

// Swizzled byte offset inside a [rows x 128B] LDS tile: 16B slot XOR'd by
// row&7 -> fragment reads land at the LDS structural floor. Staged via gll
// with PRE-SWIZZLED source slot (lane&7)^(lane>>3) (lane-pure).
__device__ inline int swz(int row, int slotByte) {
  return row * 128 + (slotByte ^ ((row & 7) << 4));
}

// ---------------------------------------------------------------------------
// Fused prep: 12 weight convert+transposes (fp32 [K,N] -> bf16 [N,K], with
// optional lo-residual output) + colsum zero-fill + x -> bf16 hi/lo.
// ---------------------------------------------------------------------------
struct WDesc { const float* src; unsigned short* dst; unsigned short* dstlo;
               int K; int N; int blk0; };
struct PrepArgs { WDesc d[12]; int nwc; };

__global__ __launch_bounds__(256) void prep_kernel(PrepArgs P,
    const float* __restrict__ x, unsigned short* __restrict__ xbf,
    unsigned short* __restrict__ xlo, float* __restrict__ csz)
{
  const int bid = blockIdx.x;
  const int tid = threadIdx.x;
  if (bid < P.nwc) {  // wconv slice
    int i = 0;
    while (i < 11 && bid >= P.d[i + 1].blk0) ++i;
    const WDesc w = P.d[i];
    const int lb = bid - w.blk0;
    const int nbn = w.N / 32;
    const int bn = (lb % nbn) * 32, bk = (lb / nbn) * 32;
    __shared__ float t[32][33];
    const int tx = tid & 31, ty = tid >> 5;
#pragma unroll
    for (int r = 0; r < 32; r += 8)
      t[ty + r][tx] = w.src[(size_t)(bk + ty + r) * w.N + bn + tx];
    __syncthreads();
#pragma unroll
    for (int r = 0; r < 32; r += 8) {
      float v = t[tx][ty + r];
      unsigned short hv = f2bf(v);
      w.dst[(size_t)(bn + ty + r) * w.K + bk + tx] = hv;
      if (w.dstlo)
        w.dstlo[(size_t)(bn + ty + r) * w.K + bk + tx] = f2bf(v - bf2f(hv));
    }
  } else if (bid < P.nwc + 64) {  // zero slice (CS1+CS2 = 16384 floats)
    int idx = (bid - P.nwc) * 256 + tid;
    csz[idx] = 0.f;
  } else {  // fconv slice: 4096 blocks, 4 floats/thread -> hi + lo
    int i = (bid - P.nwc - 64) * 256 + tid;
    float4 v = *reinterpret_cast<const float4*>(&x[(size_t)i * 4]);
    ushort4 o, ol;
    o.x = f2bf(v.x); o.y = f2bf(v.y); o.z = f2bf(v.z); o.w = f2bf(v.w);
    ol.x = f2bf(v.x - bf2f(o.x)); ol.y = f2bf(v.y - bf2f(o.y));
    ol.z = f2bf(v.z - bf2f(o.z)); ol.w = f2bf(v.w - bf2f(o.w));
    *reinterpret_cast<ushort4*>(&xbf[(size_t)i * 4]) = o;
    *reinterpret_cast<ushort4*>(&xlo[(size_t)i * 4]) = ol;
  }
}

// ---------------------------------------------------------------------------
// bf16 MFMA GEMM: BK=64, 128B LDS rows with XOR swizzle (conflict-free reads)
// staged via pre-swizzled-source global_load_lds. 32 MFMA per barrier pair.
// Epilogue modes: 0 fp32 C | 1 bf16 C | 2 bf16 C + ReLU
//   | 4 V^T layout | 5 merged QKV (N=1536).
// ---------------------------------------------------------------------------
__global__ __launch_bounds__(256) void mfma_gemm_kernel(
    const unsigned short* __restrict__ A, const unsigned short* __restrict__ BT,
    void* __restrict__ p1, void* __restrict__ p2, void* __restrict__ p3,
    int K, int N, int mode)
{
  __shared__ unsigned short As[128 * 64];  // 16KB: 128 rows x 128B
  __shared__ unsigned short Bs[128 * 64];  // 16KB
  const int tid = threadIdx.x;
  const int lane = tid & 63, wave = tid >> 6;
  const int mr = lane & 15, quad = lane >> 4;
  const int wr = wave >> 1, wc = wave & 1;
  const int m0 = blockIdx.y * 128;
  const int n0 = blockIdx.x * 128;

  f32x4 acc[4][4];
  const f32x4 zero = {0.f, 0.f, 0.f, 0.f};
#pragma unroll
  for (int i = 0; i < 4; ++i)
#pragma unroll
    for (int j = 0; j < 4; ++j) acc[i][j] = zero;

  const int r8 = lane >> 3;
  const int s8 = (lane & 7) ^ r8;
  const unsigned short* Agb = A + (size_t)(m0 + wave * 8 + r8) * K + s8 * 8;
  const unsigned short* Bgb = BT + (size_t)(n0 + wave * 8 + r8) * K + s8 * 8;
  unsigned short* Adb = As + wave * 512;   // row stride 64 shorts (128B)
  unsigned short* Bdb = Bs + wave * 512;
  char* AsB = (char*)As;
  char* BsB = (char*)Bs;
  const int xr = (mr & 7) << 4;  // read-side XOR (byte)

  for (int k0 = 0; k0 < K; k0 += 64) {
#pragma unroll
    for (int p = 0; p < 4; ++p) {
      gll16(Agb + (size_t)(p * 32) * K + k0, Adb + p * 2048);
      gll16(Bgb + (size_t)(p * 32) * K + k0, Bdb + p * 2048);
    }
    __syncthreads();  // vmcnt drain -> staged data visible
    short8 af[2][4], bf[2][4];
#pragma unroll
    for (int hh = 0; hh < 2; ++hh) {
#pragma unroll
      for (int i = 0; i < 4; ++i)
        af[hh][i] = *reinterpret_cast<const short8*>(
            AsB + (wr * 64 + i * 16 + mr) * 128 + ((((hh << 2) + quad) << 4) ^ xr));
#pragma unroll
      for (int j = 0; j < 4; ++j)
        bf[hh][j] = *reinterpret_cast<const short8*>(
            BsB + (wc * 64 + j * 16 + mr) * 128 + ((((hh << 2) + quad) << 4) ^ xr));
    }
    __builtin_amdgcn_s_setprio(1);
#pragma unroll
    for (int hh = 0; hh < 2; ++hh)
#pragma unroll
      for (int i = 0; i < 4; ++i)
#pragma unroll
        for (int j = 0; j < 4; ++j)
          acc[i][j] = __builtin_amdgcn_mfma_f32_16x16x32_bf16(af[hh][i], bf[hh][j], acc[i][j], 0, 0, 0);
    __builtin_amdgcn_s_setprio(0);
    __syncthreads();  // reads done before next tile's DMA lands
  }

  // per-wave 64x64 epilogue at (m0w, n0w)
  const int m0w = m0 + wr * 64;
  const int n0w = n0 + wc * 64;
  // C/D layout: col = lane&15, row = quad*4 + reg   [measured: m89/m91]
  int emode = mode;
  unsigned short* Cbf = (unsigned short*)p1;
  unsigned short* Vt  = (unsigned short*)p1;
  int ncol = N, coff = 0;
  if (mode == 5) {  // uniform per wave: n0w is a multiple of 64
    if (n0w < 512)       { emode = 1; Cbf = (unsigned short*)p1; ncol = 512; coff = 0; }
    else if (n0w < 1024) { emode = 1; Cbf = (unsigned short*)p2; ncol = 512; coff = 512; }
    else                 { emode = 4; Vt = (unsigned short*)p3; coff = 1024; }
  }
  if (emode == 4) {  // V^T: 4 consecutive tokens same feature -> ushort4
#pragma unroll
    for (int i = 0; i < 4; ++i)
#pragma unroll
      for (int j = 0; j < 4; ++j) {
        const int col = n0w - coff + j * 16 + mr;  // feature: h = col>>6, d = col&63
        const int row0 = m0w + i * 16 + quad * 4;  // token base (4 consecutive)
        const int bb = row0 >> 10, t0 = row0 & 1023;
        ushort4 pk;
        pk.x = f2bf(acc[i][j][0]); pk.y = f2bf(acc[i][j][1]);
        pk.z = f2bf(acc[i][j][2]); pk.w = f2bf(acc[i][j][3]);
        *reinterpret_cast<ushort4*>(
            &Vt[((size_t)((bb * Hz + (col >> 6)) * DHz + (col & 63))) * Tz + t0]) = pk;
      }
  } else if (emode == 0) {
    float* Cf = (float*)p1;
#pragma unroll
    for (int i = 0; i < 4; ++i)
#pragma unroll
      for (int j = 0; j < 4; ++j) {
        const int col = n0w + j * 16 + mr;
#pragma unroll
        for (int rr = 0; rr < 4; ++rr)
          Cf[(size_t)(m0w + i * 16 + quad * 4 + rr) * N + col] = acc[i][j][rr];
      }
  } else {
    const bool relu = (emode == 2);
#pragma unroll
    for (int i = 0; i < 4; ++i)
#pragma unroll
      for (int j = 0; j < 4; ++j) {
        const int col = n0w - coff + j * 16 + mr;
#pragma unroll
        for (int rr = 0; rr < 4; ++rr) {
          float v = acc[i][j][rr];
          if (relu) v = fmaxf(v, 0.f);
          Cbf[(size_t)(m0w + i * 16 + quad * 4 + rr) * ncol + col] = f2bf(v);
        }
      }
  }
}

// ---------------------------------------------------------------------------
// Layer-1 Q,K via bf16x3 MFMA: BK=64 swizzled gll staging (4 panels, 64KB
// LDS). Per-acc MFMA order identical -> Q/K hi/lo outputs bit-identical.
// ---------------------------------------------------------------------------
__global__ __launch_bounds__(256) void gemm_qk_mfma_kernel(
    const unsigned short* __restrict__ Xh, const unsigned short* __restrict__ Xl,
    const unsigned short* __restrict__ WQh, const unsigned short* __restrict__ WQl,
    const unsigned short* __restrict__ WKh, const unsigned short* __restrict__ WKl,
    unsigned short* __restrict__ Qhi, unsigned short* __restrict__ Qlo,
    unsigned short* __restrict__ Khi, unsigned short* __restrict__ Klo)
{
  __shared__ unsigned short Ash[128 * 64];  // 16KB each
  __shared__ unsigned short Asl[128 * 64];
  __shared__ unsigned short Bsh[128 * 64];
  __shared__ unsigned short Bsl[128 * 64];
  const int tid = threadIdx.x;
  const int lane = tid & 63, wave = tid >> 6;
  const int mr = lane & 15, quad = lane >> 4;
  const int wr = wave >> 1, wc = wave & 1;
  const int sel = blockIdx.y >> 6;
  const int m0 = (blockIdx.y & 63) * 128;
  const int n0 = blockIdx.x * 128;
  const unsigned short* Bh = sel ? WKh : WQh;
  const unsigned short* Bl = sel ? WKl : WQl;
  unsigned short* Chi = sel ? Khi : Qhi;
  unsigned short* Clo = sel ? Klo : Qlo;

  f32x4 acc[4][4];
  const f32x4 zero = {0.f, 0.f, 0.f, 0.f};
#pragma unroll
  for (int i = 0; i < 4; ++i)
#pragma unroll
    for (int j = 0; j < 4; ++j) acc[i][j] = zero;

  const int r8 = lane >> 3;
  const int s8 = (lane & 7) ^ r8;
  const unsigned short* gAh = Xh + (size_t)(m0 + wave * 8 + r8) * Dz + s8 * 8;
  const unsigned short* gAl = Xl + (size_t)(m0 + wave * 8 + r8) * Dz + s8 * 8;
  const unsigned short* gBh = Bh + (size_t)(n0 + wave * 8 + r8) * Dz + s8 * 8;
  const unsigned short* gBl = Bl + (size_t)(n0 + wave * 8 + r8) * Dz + s8 * 8;
  unsigned short* dAh = Ash + wave * 512;
  unsigned short* dAl = Asl + wave * 512;
  unsigned short* dBh = Bsh + wave * 512;
  unsigned short* dBl = Bsl + wave * 512;
  char* AhB = (char*)Ash; char* AlB = (char*)Asl;
  char* BhB = (char*)Bsh; char* BlB = (char*)Bsl;
  const int xr = (mr & 7) << 4;

  for (int k0 = 0; k0 < Dz; k0 += 64) {
#pragma unroll
    for (int p = 0; p < 4; ++p) {
      gll16(gAh + (size_t)(p * 32) * Dz + k0, dAh + p * 2048);
      gll16(gAl + (size_t)(p * 32) * Dz + k0, dAl + p * 2048);
      gll16(gBh + (size_t)(p * 32) * Dz + k0, dBh + p * 2048);
      gll16(gBl + (size_t)(p * 32) * Dz + k0, dBl + p * 2048);
    }
    __syncthreads();
    short8 ah[2][4], al[2][4], bh[2][4], bl[2][4];
#pragma unroll
    for (int hh = 0; hh < 2; ++hh) {
#pragma unroll
      for (int i = 0; i < 4; ++i) {
        const int ab = (wr * 64 + i * 16 + mr) * 128 + ((((hh << 2) + quad) << 4) ^ xr);
        ah[hh][i] = *reinterpret_cast<const short8*>(AhB + ab);
        al[hh][i] = *reinterpret_cast<const short8*>(AlB + ab);
      }
#pragma unroll
      for (int j = 0; j < 4; ++j) {
        const int bb = (wc * 64 + j * 16 + mr) * 128 + ((((hh << 2) + quad) << 4) ^ xr);
        bh[hh][j] = *reinterpret_cast<const short8*>(BhB + bb);
        bl[hh][j] = *reinterpret_cast<const short8*>(BlB + bb);
      }
    }
    __builtin_amdgcn_s_setprio(1);
#pragma unroll
    for (int hh = 0; hh < 2; ++hh)
#pragma unroll
      for (int i = 0; i < 4; ++i)
#pragma unroll
        for (int j = 0; j < 4; ++j) {
          acc[i][j] = __builtin_amdgcn_mfma_f32_16x16x32_bf16(al[hh][i], bh[hh][j], acc[i][j], 0, 0, 0);
          acc[i][j] = __builtin_amdgcn_mfma_f32_16x16x32_bf16(ah[hh][i], bl[hh][j], acc[i][j], 0, 0, 0);
          acc[i][j] = __builtin_amdgcn_mfma_f32_16x16x32_bf16(ah[hh][i], bh[hh][j], acc[i][j], 0, 0, 0);
        }
    __builtin_amdgcn_s_setprio(0);
    __syncthreads();
  }

  const int m0w = m0 + wr * 64;
  const int n0w = n0 + wc * 64;
#pragma unroll
  for (int i = 0; i < 4; ++i)
#pragma unroll
    for (int j = 0; j < 4; ++j) {
      const int col = n0w + j * 16 + mr;
#pragma unroll
      for (int rr = 0; rr < 4; ++rr) {
        const size_t row = (size_t)(m0w + i * 16 + quad * 4 + rr);
        float v = acc[i][j][rr];
        unsigned short hv = f2bf(v);
        Chi[row * Dz + col] = hv;
        Clo[row * Dz + col] = f2bf(v - bf2f(hv));
      }
    }
}

// ---------------------------------------------------------------------------
// Layer-1 FUSED attention: pass 0 computes z (cheap plain-bf16 QK^T over
// gll-staged K-hi tiles, TWO tiles per barrier pair using the idle Ksl
// buffer — tile order unchanged -> z bits unchanged); pass 1 is the proven
// ctx loop (bf16x3 QK^T + deterministic colsum + PV). setprio wraps MFMA
// clusters (schedule-only). All arithmetic values/order and PART slots are
// bit-identical to rounds 4-10.
// ---------------------------------------------------------------------------
__global__ __launch_bounds__(256) void attn_fused_kernel(
    const unsigned short* __restrict__ Qh, const unsigned short* __restrict__ Ql,
    const unsigned short* __restrict__ Kh, const unsigned short* __restrict__ Kl,
    const unsigned short* __restrict__ Vt,
    unsigned short* __restrict__ ctx, float* __restrict__ part)
{
  __shared__ unsigned short Ksh[64 * 64];  // 8KB: 64 keys x 128B (swizzled)
  __shared__ unsigned short Ksl[64 * 64];  // 8KB
  __shared__ unsigned short Vsh[64 * 64];  // 8KB
  __shared__ unsigned short Pld[64][76];   // 9.5KB
  __shared__ float CSPt[4][64];
  const int tid = threadIdx.x;
  const int lane = tid & 63, wave = tid >> 6;
  const int c = lane & 15, quad = lane >> 4;
  int b, h, qt;
  attn_decode(blockIdx.x, b, h, qt);
  const size_t bT = (size_t)b * Tz;
  const int qrow = qt * 64 + wave * 16;
  const int hoff = h * DHz;
  const int lidx = b * 128 + h * 16 + qt;  // logical PART slot

  const size_t qbase = (bT + qrow + c) * Dz + hoff + quad * 8;
  short8 q0h = *reinterpret_cast<const short8*>(Qh + qbase);
  short8 q1h = *reinterpret_cast<const short8*>(Qh + qbase + 32);
  short8 q0l = *reinterpret_cast<const short8*>(Ql + qbase);
  short8 q1l = *reinterpret_cast<const short8*>(Ql + qbase + 32);

  // gll staging coords: instr = 8 rows x 8 slots; src slot pre-swizzled.
  const int r8 = lane >> 3;
  const int s8 = (lane & 7) ^ r8;
  const unsigned short* khg = Kh + (bT + wave * 8 + r8) * Dz + hoff + s8 * 8;
  const unsigned short* klg = Kl + (bT + wave * 8 + r8) * Dz + hoff + s8 * 8;
  const unsigned short* vtg = Vt + ((size_t)((b * Hz + h) * DHz) + wave * 8 + r8) * Tz + s8 * 8;
  unsigned short* KshW = Ksh + wave * 512;
  unsigned short* KslW = Ksl + wave * 512;
  unsigned short* VshW = Vsh + wave * 512;
  char* KshB = (char*)Ksh;
  char* KslB = (char*)Ksl;
  char* VshB = (char*)Vsh;

  const f32x4 zf = {0.f, 0.f, 0.f, 0.f};

  // ---------------- pass 0: z (plain bf16, K-hi only, 2 tiles/barrier) ----
  float z[4] = {0.f, 0.f, 0.f, 0.f};
  for (int tt = 0; tt < 8; ++tt) {
    const int k0 = tt * 128;
    gll16(khg + (size_t)k0 * Dz, KshW);
    gll16(khg + (size_t)(k0 + 32) * Dz, KshW + 2048);
    gll16(khg + (size_t)(k0 + 64) * Dz, KslW);
    gll16(khg + (size_t)(k0 + 96) * Dz, KslW + 2048);
    __syncthreads();
    __builtin_amdgcn_s_setprio(1);
#pragma unroll
    for (int half = 0; half < 2; ++half) {
      char* Kb = half ? KslB : KshB;
#pragma unroll
      for (int sub = 0; sub < 4; ++sub) {
        const int row = sub * 16 + c;
        short8 kh0 = *reinterpret_cast<const short8*>(Kb + swz(row, quad * 16));
        short8 kh1 = *reinterpret_cast<const short8*>(Kb + swz(row, 64 + quad * 16));
        f32x4 aA = zf, aB = zf;
        aA = __builtin_amdgcn_mfma_f32_16x16x32_bf16(q0h, kh0, aA, 0, 0, 0);
        aB = __builtin_amdgcn_mfma_f32_16x16x32_bf16(q1h, kh1, aB, 0, 0, 0);
#pragma unroll
        for (int rr = 0; rr < 4; ++rr) z[rr] += __expf((aA[rr] + aB[rr]) * 0.125f);
      }
    }
    __builtin_amdgcn_s_setprio(0);
    __syncthreads();
  }
#pragma unroll
  for (int w = 1; w < 16; w <<= 1) {
#pragma unroll
    for (int rr = 0; rr < 4; ++rr) z[rr] += __shfl_xor(z[rr], w);
  }
  float invz[4];
#pragma unroll
  for (int rr = 0; rr < 4; ++rr) invz[rr] = 1.f / z[rr];

  // ---------------- pass 1: P, colsum, PV ----------------
  f32x4 ot[4] = {zf, zf, zf, zf};
  for (int t = 0; t < 16; ++t) {
    const int k0 = t * 64;
    gll16(khg + (size_t)k0 * Dz, KshW);
    gll16(khg + (size_t)(k0 + 32) * Dz, KshW + 2048);
    gll16(klg + (size_t)k0 * Dz, KslW);
    gll16(klg + (size_t)(k0 + 32) * Dz, KslW + 2048);
    gll16(vtg + k0, VshW);
    gll16(vtg + (size_t)32 * Tz + k0, VshW + 2048);
    __syncthreads();  // staged data visible

    // ---- QK^T subtiles (bf16x3, 2-acc split) ----
#pragma unroll
    for (int sub = 0; sub < 4; ++sub) {
      const int row = sub * 16 + c;
      short8 kh0 = *reinterpret_cast<const short8*>(KshB + swz(row, quad * 16));
      short8 kh1 = *reinterpret_cast<const short8*>(KshB + swz(row, 64 + quad * 16));
      short8 kl0 = *reinterpret_cast<const short8*>(KslB + swz(row, quad * 16));
      short8 kl1 = *reinterpret_cast<const short8*>(KslB + swz(row, 64 + quad * 16));
      f32x4 aA = zf, aB = zf;
      __builtin_amdgcn_s_setprio(1);
      aA = __builtin_amdgcn_mfma_f32_16x16x32_bf16(q0h, kh0, aA, 0, 0, 0);
      aB = __builtin_amdgcn_mfma_f32_16x16x32_bf16(q1h, kh1, aB, 0, 0, 0);
      aA = __builtin_amdgcn_mfma_f32_16x16x32_bf16(q0h, kl0, aA, 0, 0, 0);
      aB = __builtin_amdgcn_mfma_f32_16x16x32_bf16(q1h, kl1, aB, 0, 0, 0);
      aA = __builtin_amdgcn_mfma_f32_16x16x32_bf16(q0l, kh0, aA, 0, 0, 0);
      aB = __builtin_amdgcn_mfma_f32_16x16x32_bf16(q1l, kh1, aB, 0, 0, 0);
      __builtin_amdgcn_s_setprio(0);
      float p[4];
#pragma unroll
      for (int rr = 0; rr < 4; ++rr)
        p[rr] = __expf((aA[rr] + aB[rr]) * 0.125f) * invz[rr];
      float cs = p[0] + p[1] + p[2] + p[3];
      cs += __shfl_xor(cs, 16);
      cs += __shfl_xor(cs, 32);
      if (quad == 0) CSPt[wave][sub * 16 + c] = cs;  // key visited once
#pragma unroll
      for (int rr = 0; rr < 4; ++rr)
        Pld[(wave << 4) + quad * 4 + rr][sub * 16 + c] = f2bf(p[rr]);
    }

    // ---- PV from LDS ----
    union { short8 v; ushort4 hh[2]; } pb0, pb1;
    pb0.hh[0] = *reinterpret_cast<const ushort4*>(&Pld[(wave << 4) + c][quad * 8]);
    pb0.hh[1] = *reinterpret_cast<const ushort4*>(&Pld[(wave << 4) + c][quad * 8 + 4]);
    pb1.hh[0] = *reinterpret_cast<const ushort4*>(&Pld[(wave << 4) + c][32 + quad * 8]);
    pb1.hh[1] = *reinterpret_cast<const ushort4*>(&Pld[(wave << 4) + c][32 + quad * 8 + 4]);
    __builtin_amdgcn_s_setprio(1);
#pragma unroll
    for (int ds = 0; ds < 4; ++ds) {
      const int row = ds * 16 + c;
      short8 v0 = *reinterpret_cast<const short8*>(VshB + swz(row, quad * 16));
      short8 v1 = *reinterpret_cast<const short8*>(VshB + swz(row, 64 + quad * 16));
      ot[ds] = __builtin_amdgcn_mfma_f32_16x16x32_bf16(v0, pb0.v, ot[ds], 0, 0, 0);
      ot[ds] = __builtin_amdgcn_mfma_f32_16x16x32_bf16(v1, pb1.v, ot[ds], 0, 0, 0);
    }
    __builtin_amdgcn_s_setprio(0);
    __syncthreads();  // all LDS reads done; CSPt complete across waves

    // ---- deterministic per-tile colsum combine (same 4-addend order) ----
    if (tid < 64) {
      float v = ((CSPt[0][tid] + CSPt[1][tid]) + CSPt[2][tid]) + CSPt[3][tid];
      part[(size_t)lidx * 1024 + k0 + tid] = v * (1.f / Hz);
    }
  }

  const size_t cb = (bT + qrow + c) * Dz + hoff;
#pragma unroll
  for (int ds = 0; ds < 4; ++ds) {
    ushort4 pk;
    pk.x = f2bf(ot[ds][0]); pk.y = f2bf(ot[ds][1]);
    pk.z = f2bf(ot[ds][2]); pk.w = f2bf(ot[ds][3]);
    *reinterpret_cast<ushort4*>(&ctx[cb + ds * 16 + quad * 4]) = pk;
  }
}

// ---------------------------------------------------------------------------
// Layer-2 MFMA attention (masked), k-tile range skipping, gll-staged K/V,
// setprio on MFMA clusters. Arithmetic values/order identical.
// ---------------------------------------------------------------------------
__global__ __launch_bounds__(256) void attn_mfma2_kernel(
    const unsigned short* __restrict__ Qh, const unsigned short* __restrict__ Kh,
    const unsigned short* __restrict__ Vt, const int* __restrict__ ids,
    const int* __restrict__ wst,
    unsigned short* __restrict__ ctx, float* __restrict__ colsum)
{
  __shared__ unsigned short Ksh[64 * 64];  // 8KB (swizzled)
  __shared__ unsigned short Vsh[64 * 64];  // 8KB (swizzled)
  __shared__ unsigned short Pld[64][76];
  __shared__ float csb[1024];

  const int tid = threadIdx.x;
  const int lane = tid & 63, wave = tid >> 6;
  const int c = lane & 15, quad = lane >> 4;
  int b, h, qt;
  attn_decode(blockIdx.x, b, h, qt);
  const size_t bT = (size_t)b * Tz;
  const int qrow = qt * 64 + wave * 16;
  const int hoff = h * DHz;

  for (int i = tid; i < 1024; i += 256) csb[i] = 0.f;

  const int id_lo = ids[bT + qt * 64];
  const int id_hi = ids[bT + qt * 64 + 63];
  const int klo = wst[b * (Tz + 1) + id_lo];
  const int khi = wst[b * (Tz + 1) + id_hi + 1];
  const int t0 = klo >> 6, t1 = (khi - 1) >> 6;

  const size_t qbase = (bT + qrow + c) * Dz + hoff + quad * 8;
  short8 q0 = *reinterpret_cast<const short8*>(Qh + qbase);
  short8 q1 = *reinterpret_cast<const short8*>(Qh + qbase + 32);

  int qid[4];
#pragma unroll
  for (int rr = 0; rr < 4; ++rr) qid[rr] = ids[bT + qrow + quad * 4 + rr];

  const int r8 = lane >> 3;
  const int s8 = (lane & 7) ^ r8;
  const unsigned short* khg = Kh + (bT + wave * 8 + r8) * Dz + hoff + s8 * 8;
  const unsigned short* vtg = Vt + ((size_t)((b * Hz + h) * DHz) + wave * 8 + r8) * Tz + s8 * 8;
  unsigned short* KshW = Ksh + wave * 512;
  unsigned short* VshW = Vsh + wave * 512;
  char* KshB = (char*)Ksh;
  char* VshB = (char*)Vsh;
  __syncthreads();  // csb zeros visible before pass-2 atomics

  const f32x4 zf = {0.f, 0.f, 0.f, 0.f};

  // pass 1: z (stage Kh per tile)
  float z[4] = {0.f, 0.f, 0.f, 0.f};
  for (int t = t0; t <= t1; ++t) {
    const int k0 = t * 64;
    gll16(khg + (size_t)k0 * Dz, KshW);
    gll16(khg + (size_t)(k0 + 32) * Dz, KshW + 2048);
    __syncthreads();
    __builtin_amdgcn_s_setprio(1);
#pragma unroll
    for (int sub = 0; sub < 4; ++sub) {
      const int row = sub * 16 + c;
      short8 kh0 = *reinterpret_cast<const short8*>(KshB + swz(row, quad * 16));
      short8 kh1 = *reinterpret_cast<const short8*>(KshB + swz(row, 64 + quad * 16));
      f32x4 acc = zf;
      acc = __builtin_amdgcn_mfma_f32_16x16x32_bf16(q0, kh0, acc, 0, 0, 0);
      acc = __builtin_amdgcn_mfma_f32_16x16x32_bf16(q1, kh1, acc, 0, 0, 0);
      int kidv = ids[bT + k0 + sub * 16 + c];
#pragma unroll
      for (int rr = 0; rr < 4; ++rr) {
        float e = __expf(acc[rr] * 0.125f);
        if (qid[rr] != kidv) e = 0.f;
        z[rr] += e;
      }
    }
    __builtin_amdgcn_s_setprio(0);
    __syncthreads();
  }
#pragma unroll
  for (int w = 1; w < 16; w <<= 1) {
#pragma unroll
    for (int rr = 0; rr < 4; ++rr) z[rr] += __shfl_xor(z[rr], w);
  }
  float invz[4];
#pragma unroll
  for (int rr = 0; rr < 4; ++rr) invz[rr] = 1.f / z[rr];

  // pass 2: P, colsum, PV (stage Kh + V per tile)
  f32x4 ot[4] = {zf, zf, zf, zf};
  for (int t = t0; t <= t1; ++t) {
    const int k0 = t * 64;
    gll16(khg + (size_t)k0 * Dz, KshW);
    gll16(khg + (size_t)(k0 + 32) * Dz, KshW + 2048);
    gll16(vtg + k0, VshW);
    gll16(vtg + (size_t)32 * Tz + k0, VshW + 2048);
    __syncthreads();
#pragma unroll
    for (int sub = 0; sub < 4; ++sub) {
      const int row = sub * 16 + c;
      short8 kh0 = *reinterpret_cast<const short8*>(KshB + swz(row, quad * 16));
      short8 kh1 = *reinterpret_cast<const short8*>(KshB + swz(row, 64 + quad * 16));
      f32x4 acc = zf;
      __builtin_amdgcn_s_setprio(1);
      acc = __builtin_amdgcn_mfma_f32_16x16x32_bf16(q0, kh0, acc, 0, 0, 0);
      acc = __builtin_amdgcn_mfma_f32_16x16x32_bf16(q1, kh1, acc, 0, 0, 0);
      __builtin_amdgcn_s_setprio(0);
      int kidv = ids[bT + k0 + sub * 16 + c];
      float p[4];
#pragma unroll
      for (int rr = 0; rr < 4; ++rr) {
        float e = __expf(acc[rr] * 0.125f);
        if (qid[rr] != kidv) e = 0.f;
        p[rr] = e * invz[rr];
      }
      float cs = p[0] + p[1] + p[2] + p[3];
      cs += __shfl_xor(cs, 16);
      cs += __shfl_xor(cs, 32);
      if (quad == 0) atomicAdd(&csb[k0 + sub * 16 + c], cs);
#pragma unroll
      for (int rr = 0; rr < 4; ++rr)
        Pld[(wave << 4) + quad * 4 + rr][sub * 16 + c] = f2bf(p[rr]);
    }
    union { short8 v; ushort4 hh[2]; } pb0, pb1;
    pb0.hh[0] = *reinterpret_cast<const ushort4*>(&Pld[(wave << 4) + c][quad * 8]);
    pb0.hh[1] = *reinterpret_cast<const ushort4*>(&Pld[(wave << 4) + c][quad * 8 + 4]);
    pb1.hh[0] = *reinterpret_cast<const ushort4*>(&Pld[(wave << 4) + c][32 + quad * 8]);
    pb1.hh[1] = *reinterpret_cast<const ushort4*>(&Pld[(wave << 4) + c][32 + quad * 8 + 4]);
    __builtin_amdgcn_s_setprio(1);
#pragma unroll
    for (int ds = 0; ds < 4; ++ds) {
      const int row = ds * 16 + c;
      short8 v0 = *reinterpret_cast<const short8*>(VshB + swz(row, quad * 16));
      short8 v1 = *reinterpret_cast<const short8*>(VshB + swz(row, 64 + quad * 16));
      ot[ds] = __builtin_amdgcn_mfma_f32_16x16x32_bf16(v0, pb0.v, ot[ds], 0, 0, 0);
      ot[ds] = __builtin_amdgcn_mfma_f32_16x16x32_bf16(v1, pb1.v, ot[ds], 0, 0, 0);
    }
    __builtin_amdgcn_s_setprio(0);
    __syncthreads();  // LDS reads done before next tile's staging
  }

  const size_t cb = (bT + qrow + c) * Dz + hoff;
#pragma unroll
  for (int ds = 0; ds < 4; ++ds) {
    ushort4 pk;
    pk.x = f2bf(ot[ds][0]); pk.y = f2bf(ot[ds][1]);
    pk.z = f2bf(ot[ds][2]); pk.w = f2bf(ot[ds][3]);
    *reinterpret_cast<ushort4*>(&ctx[cb + ds * 16 + quad * 4]) = pk;
  }
  __syncthreads();
  for (int i = tid; i < 1024; i += 256)
    atomicAdd(&colsum[bT + i], csb[i] * (1.f / Hz));
}

// ---------------------------------------------------------------------------
// out = LayerNorm(resid + delta). resid fp32 (residf) if non-null else bf16.
// ---------------------------------------------------------------------------
__global__ __launch_bounds__(256) void ln_kernel(const float* __restrict__ residf,
    const unsigned short* __restrict__ residbf, const float* __restrict__ delta,
    float* __restrict__ outf, unsigned short* __restrict__ outbf)
{
  const size_t base = (size_t)blockIdx.x * Dz;
  const int tid = threadIdx.x;
  float r0, r1;
  if (residf) {
    r0 = residf[base + tid]; r1 = residf[base + tid + 256];
  } else {
    r0 = bf2f(residbf[base + tid]); r1 = bf2f(residbf[base + tid + 256]);
  }
  float x0 = r0 + delta[base + tid];
  float x1 = r1 + delta[base + tid + 256];
  __shared__ float red[4];
  float s = x0 + x1;
#pragma unroll
  for (int off = 32; off; off >>= 1) s += __shfl_down(s, off);
  if ((tid & 63) == 0) red[tid >> 6] = s;
  __syncthreads();
  const float mean = (red[0] + red[1] + red[2] + red[3]) * (1.f / Dz);
  __syncthreads();
  float d0 = x0 - mean, d1 = x1 - mean;
  float v = d0 * d0 + d1 * d1;
#pragma unroll
  for (int off = 32; off; off >>= 1) v += __shfl_down(v, off);
  if ((tid & 63) == 0) red[tid >> 6] = v;
  __syncthreads();
  const float var = (red[0] + red[1] + red[2] + red[3]) * (1.f / Dz);
  const float rstd = rsqrtf(var + 1e-5f);
  float y0 = d0 * rstd, y1 = d1 * rstd;
  if (outf) {
    outf[base + tid] = y0;
    outf[base + tid + 256] = y1;
  }
  outbf[base + tid] = f2bf(y0);
  outbf[base + tid + 256] = f2bf(y1);
}

// ---------------------------------------------------------------------------
// Per batch: FUSED colsum reduce (identical ascending-j order per key ->
// CS1 bits identical, never materialized) + min-max normalize + threshold
// + run-length window scan (ballot + bit-scan, round 7 proven).
// ---------------------------------------------------------------------------
__global__ __launch_bounds__(256) void window_ids_kernel(const float* __restrict__ part,
    int* __restrict__ ids, int* __restrict__ wst, int* __restrict__ nwin)
{
  const int b = blockIdx.x, tid = threadIdx.x;
  __shared__ float vals[Tz];
  __shared__ int swst[Tz + 1];
  __shared__ unsigned long long words[16];
  __shared__ float rmin[4], rmax[4];
  __shared__ int snw;
  // fused deterministic reduce: cs[k] = sum_j part[(b*128+j)*1024+k], j asc.
  for (int k = tid; k < Tz; k += 256) {
    const float* p = part + (size_t)(b * 128) * 1024 + k;
    float s = 0.f;
    for (int j = 0; j < 128; ++j) s += p[(size_t)j * 1024];
    vals[k] = s;
  }
  __syncthreads();
  float mn = INFINITY, mx = -INFINITY;
  for (int t = tid; t < Tz; t += 256) {
    float v = vals[t];
    mn = fminf(mn, v); mx = fmaxf(mx, v);
  }
#pragma unroll
  for (int off = 32; off; off >>= 1) {
    mn = fminf(mn, __shfl_down(mn, off));
    mx = fmaxf(mx, __shfl_down(mx, off));
  }
  if ((tid & 63) == 0) { rmin[tid >> 6] = mn; rmax[tid >> 6] = mx; }
  __syncthreads();
  mn = fminf(fminf(rmin[0], rmin[1]), fminf(rmin[2], rmin[3]));
  mx = fmaxf(fmaxf(rmax[0], rmax[1]), fmaxf(rmax[2], rmax[3]));
  const float inv = 1.f / (mx - mn + 1e-8f);
  const int lane = tid & 63, wave = tid >> 6;
#pragma unroll
  for (int pass = 0; pass < 4; ++pass) {
    const int t = pass * 256 + wave * 64 + lane;
    const bool bit = ((vals[t] - mn) * inv) >= 0.5f;  // identical threshold op
    unsigned long long m = __ballot(bit);
    if (lane == 0) words[pass * 4 + wave] = m;
  }
  __syncthreads();
  if (tid == 0) {
    int start = 0, wid = 0;
    swst[0] = 0;
    unsigned long long carry = 0;
    for (int i = 0; i < 16; ++i) {
      const unsigned long long wi = words[i];
      unsigned long long tr = wi ^ ((wi << 1) | carry);
      carry = wi >> 63;
      if (i == 0) tr &= ~1ULL;  // t=0 is not a transition
      while (tr) {
        const int t = i * 64 + __builtin_ctzll(tr);
        tr &= tr - 1;
        if (start + 1 != t) { start = t; ++wid; swst[wid] = t; }
      }
    }
    nwin[b] = wid + 1;
    swst[wid + 1] = Tz;
    snw = wid + 1;
  }
  __syncthreads();
  const int nw = snw;
  for (int j = tid; j <= nw; j += 256) wst[b * (Tz + 1) + j] = swst[j];
  for (int t = tid; t < Tz; t += 256) {
    int lo = 0, hi = nw;  // swst[0]=0 <= t, swst[nw]=Tz > t
    while (hi - lo > 1) {
      const int mid = (lo + hi) >> 1;
      if (swst[mid] <= t) lo = mid; else hi = mid;
    }
    ids[b * Tz + t] = lo;
  }
}

// ---------------------------------------------------------------------------
// wl[b,:] = softmax over keys of layer-2 colsum.
// ---------------------------------------------------------------------------
__global__ __launch_bounds__(256) void wl_softmax_kernel(const float* __restrict__ cs,
                                                         float* __restrict__ wl)
{
  const int b = blockIdx.x, tid = threadIdx.x;
  __shared__ float vals[Tz];
  __shared__ float red[4];
  float mx = -INFINITY;
  for (int t = tid; t < Tz; t += 256) {
    float v = cs[b * Tz + t];
    vals[t] = v;
    mx = fmaxf(mx, v);
  }
#pragma unroll
  for (int off = 32; off; off >>= 1) mx = fmaxf(mx, __shfl_down(mx, off));
  if ((tid & 63) == 0) red[tid >> 6] = mx;
  __syncthreads();
  mx = fmaxf(fmaxf(red[0], red[1]), fmaxf(red[2], red[3]));
  __syncthreads();
  float se = 0.f;
  for (int t = tid; t < Tz; t += 256) {
    float e = expf(vals[t] - mx);
    vals[t] = e;
    se += e;
  }
#pragma unroll
  for (int off = 32; off; off >>= 1) se += __shfl_down(se, off);
  if ((tid & 63) == 0) red[tid >> 6] = se;
  __syncthreads();
  const float inv = 1.f / (red[0] + red[1] + red[2] + red[3]);
  for (int t = tid; t < Tz; t += 256) wl[b * Tz + t] = vals[t] * inv;
}

// ---------------------------------------------------------------------------
// Fused outputs: word_tokens (blocks 0..8191), winmap (8192..16383),
// copy_x (16384..20479).
// ---------------------------------------------------------------------------
__global__ __launch_bounds__(256) void outputs_kernel(
    const unsigned short* __restrict__ outl, const float* __restrict__ wl,
    const int* __restrict__ wst, const int* __restrict__ nwin,
    const int* __restrict__ ids, const float* __restrict__ x,
    float* __restrict__ out, float* __restrict__ out2)
{
  const int bid = blockIdx.x;
  const int tid = threadIdx.x;
  if (bid < 8192) {  // word_tokens
    const int w = bid & (Tz - 1);
    const int b = bid >> 10;
    float a0 = 0.f, a1 = 0.f;
    if (w < nwin[b]) {
      const int s = wst[b * (Tz + 1) + w], e = wst[b * (Tz + 1) + w + 1];
      for (int t = s; t < e; ++t) {
        const float sc = wl[b * Tz + t];
        const unsigned short* p = &outl[((size_t)(b * Tz + t)) * Dz];
        a0 += bf2f(p[tid]) * sc;
        a1 += bf2f(p[tid + 256]) * sc;
      }
    }
    float* o = &out[((size_t)(b * 2 * Tz + w)) * Dz];
    o[tid] = a0;
    o[tid + 256] = a1;
  } else if (bid < 16384) {  // winmap
    const int lb = bid - 8192;
    const int w = lb & (Tz - 1);
    const int b = lb >> 10;
    const int j = tid * 4;
    int4 id4 = *reinterpret_cast<const int4*>(&ids[b * Tz + j]);
    float4 v;
    v.x = (id4.x == w) ? 1.f : 0.f;
    v.y = (id4.y == w) ? 1.f : 0.f;
    v.z = (id4.z == w) ? 1.f : 0.f;
    v.w = (id4.w == w) ? 1.f : 0.f;
    *reinterpret_cast<float4*>(&out2[((size_t)(b * Tz + w)) * Tz + j]) = v;
  } else {  // copy_x
    size_t i = (size_t)(bid - 16384) * 256 + tid;
    size_t idx = i * 4;
    size_t rowi = idx >> 9;
    size_t d = idx & 511;
    size_t b = rowi >> 10, t = rowi & 1023;
    float4 v = *reinterpret_cast<const float4*>(&x[idx]);
    *reinterpret_cast<float4*>(&out[(((b * 2 * Tz) + Tz + t) << 9) + d]) = v;
  }
}

// ---------------------------------------------------------------------------
// Orchestration: 20 dispatches. colsum_reduce fused into window_ids; setprio
// on MFMA clusters; pass-0 double-tile staging in attn_fused.
// ---------------------------------------------------------------------------
extern "C" void kernel_launch(void* const* d_in, const int* in_sizes, int n_in,
                              void* d_out, int out_size, void* d_ws, size_t ws_size,
                              hipStream_t stream)
{
  (void)in_sizes; (void)n_in; (void)out_size; (void)ws_size;
  const float* x     = (const float*)d_in[0];
  const float* vqkv  = (const float*)d_in[1];
  const float* voutw = (const float*)d_in[2];
  const float* vw1   = (const float*)d_in[3];
  const float* vw2   = (const float*)d_in[4];
  const float* lqkv  = (const float*)d_in[5];
  const float* loutw = (const float*)d_in[6];
  const float* lw1   = (const float*)d_in[7];
  const float* lw2   = (const float*)d_in[8];
  float* out = (float*)d_out;
  float* ws  = (float*)d_ws;

  unsigned short* QLbf = (unsigned short*)(ws + 0);        // bf16 Q lo (L1)
  unsigned short* KLbf = (unsigned short*)(ws + 2097152);  // bf16 K lo (L1)
  float* PROJ = ws + 0;         // written after attn_fused (QL/KL dead)
  float* Y1   = ws + 4194304;
  unsigned short* QHbf = (unsigned short*)(ws + 8388608);   // bf16 Q hi (L1+L2)
  unsigned short* KHbf = (unsigned short*)(ws + 10485760);  // bf16 K hi (L1+L2)
  unsigned short* VT   = (unsigned short*)(ws + 12582912);
  unsigned short* SLOT1 = (unsigned short*)(ws + 14680064); // attn ctx bf16
  unsigned short* SLOT2 = (unsigned short*)(ws + 16777216); // LN bf16 out
  unsigned short* HIDbf = (unsigned short*)(ws + 18874368); // FFN hidden
  unsigned short* XBF   = (unsigned short*)(ws + 18874368); // x hi bf16 (pre-FFN)
  float* PART = ws + 18874368;  // colsum block partials (1024x1024); written
                                // by attn_fused after XBF/XLO dead, dead by FFN1
  unsigned short* XLO = (unsigned short*)(ws + 20971520);   // x lo bf16
  // bf16 transposed weights (WLQ0..2 contiguous -> merged [1536,512] matrix)
  unsigned short* WVQV = (unsigned short*)(ws + 27262976);
  unsigned short* WVO  = (unsigned short*)(ws + 27394048);
  unsigned short* WV1  = (unsigned short*)(ws + 27525120);
  unsigned short* WV2  = (unsigned short*)(ws + 28049408);
  unsigned short* WLQ0 = (unsigned short*)(ws + 28573696);
  unsigned short* WLQ1 = (unsigned short*)(ws + 28704768);
  unsigned short* WLQ2 = (unsigned short*)(ws + 28835840);
  unsigned short* WLO  = (unsigned short*)(ws + 28966912);
  unsigned short* WL1  = (unsigned short*)(ws + 29097984);
  unsigned short* WL2  = (unsigned short*)(ws + 29622272);
  // small buffers
  float* CS1   = ws + 30146560;  // zero-filled (CS2 follows contiguously)
  float* CS2   = ws + 30154752;
  float* WLs   = ws + 30162944;
  int*   IDS   = (int*)(ws + 30171136);
  int*   WST   = (int*)(ws + 30179328);
  int*   NWIN  = (int*)(ws + 30187776);
  // layer-1 Q/K weights, bf16 transposed hi/lo (512x512 each = 131072 floats)
  unsigned short* WQH = (unsigned short*)(ws + 30261504);
  unsigned short* WQL = (unsigned short*)(ws + 30392576);
  unsigned short* WKH = (unsigned short*)(ws + 30523648);
  unsigned short* WKL = (unsigned short*)(ws + 30654720);

  dim3 blk(256);

  // ---- fused prep: 12 wconv + zero + fconv(hi/lo) ----
  PrepArgs P;
  auto setw = [&](int i, const float* s, unsigned short* d, unsigned short* dl,
                  int K, int N, int b0) {
    P.d[i].src = s; P.d[i].dst = d; P.d[i].dstlo = dl;
    P.d[i].K = K; P.d[i].N = N; P.d[i].blk0 = b0;
  };
  int b0 = 0;
  setw(0, vqkv + 2 * Dz * Dz, WVQV, nullptr, Dz, Dz, b0); b0 += 256;
  setw(1, voutw, WVO, nullptr, Dz, Dz, b0); b0 += 256;
  setw(2, vw1, WV1, nullptr, Dz, FFz, b0); b0 += 1024;
  setw(3, vw2, WV2, nullptr, FFz, Dz, b0); b0 += 1024;
  setw(4, lqkv + 0 * Dz * Dz, WLQ0, nullptr, Dz, Dz, b0); b0 += 256;
  setw(5, lqkv + 1 * Dz * Dz, WLQ1, nullptr, Dz, Dz, b0); b0 += 256;
  setw(6, lqkv + 2 * Dz * Dz, WLQ2, nullptr, Dz, Dz, b0); b0 += 256;
  setw(7, loutw, WLO, nullptr, Dz, Dz, b0); b0 += 256;
  setw(8, lw1, WL1, nullptr, Dz, FFz, b0); b0 += 1024;
  setw(9, lw2, WL2, nullptr, FFz, Dz, b0); b0 += 1024;
  setw(10, vqkv + 0 * Dz * Dz, WQH, WQL, Dz, Dz, b0); b0 += 256;
  setw(11, vqkv + 1 * Dz * Dz, WKH, WKL, Dz, Dz, b0); b0 += 256;
  P.nwc = b0;  // 6144
  prep_kernel<<<dim3(P.nwc + 64 + 4096), blk, 0, stream>>>(P, x, XBF, XLO, CS1);

  auto mgemm = [&](const unsigned short* A, const unsigned short* BT, void* p1,
                   void* p2, void* p3, int K, int N, int mode) {
    mfma_gemm_kernel<<<dim3(N / 128, Mz / 128), dim3(256), 0, stream>>>(
        A, BT, p1, p2, p3, K, N, mode);
  };

  // ---------------- layer 1 (vanilla) ----------------
  gemm_qk_mfma_kernel<<<dim3(4, 128), dim3(256), 0, stream>>>(
      XBF, XLO, WQH, WQL, WKH, WKL, QHbf, QLbf, KHbf, KLbf);
  mgemm(XBF, WVQV, VT, nullptr, nullptr, Dz, Dz, 4);        // V -> V^T (XBF/XLO dead)
  attn_fused_kernel<<<dim3(Bz * Hz * 16), blk, 0, stream>>>(
      QHbf, QLbf, KHbf, KLbf, VT, SLOT1, PART);
  window_ids_kernel<<<dim3(Bz), blk, 0, stream>>>(PART, IDS, WST, NWIN);
  mgemm(SLOT1, WVO, PROJ, nullptr, nullptr, Dz, Dz, 0);     // proj (QL/KL dead)
  ln_kernel<<<dim3(Mz), blk, 0, stream>>>(x, nullptr, PROJ, Y1, SLOT2);
  mgemm(SLOT2, WV1, HIDbf, nullptr, nullptr, Dz, FFz, 2);   // FFN1 (PART dead)
  mgemm(HIDbf, WV2, PROJ, nullptr, nullptr, FFz, Dz, 0);    // FFN2
  ln_kernel<<<dim3(Mz), blk, 0, stream>>>(Y1, nullptr, PROJ, nullptr, SLOT2);

  // ---------------- layer 2 (block-diagonal window mask) ----------------
  mgemm(SLOT2, WLQ0, QHbf, KHbf, VT, Dz, 3 * Dz, 5);        // merged QKV
  attn_mfma2_kernel<<<dim3(Bz * Hz * 16), blk, 0, stream>>>(
      QHbf, KHbf, VT, IDS, WST, SLOT1, CS2);
  mgemm(SLOT1, WLO, PROJ, nullptr, nullptr, Dz, Dz, 0);
  ln_kernel<<<dim3(Mz), blk, 0, stream>>>(nullptr, SLOT2, PROJ, Y1, SLOT2);
  mgemm(SLOT2, WL1, HIDbf, nullptr, nullptr, Dz, FFz, 2);
  mgemm(HIDbf, WL2, PROJ, nullptr, nullptr, FFz, Dz, 0);
  ln_kernel<<<dim3(Mz), blk, 0, stream>>>(Y1, nullptr, PROJ, nullptr, SLOT2);

  // ---------------- pooling + outputs ----------------
  wl_softmax_kernel<<<dim3(Bz), blk, 0, stream>>>(CS2, WLs);
  outputs_kernel<<<dim3(20480), blk, 0, stream>>>(SLOT2, WLs, WST, NWIN, IDS, x,
                                                  out, out + (size_t)Bz * 2 * Tz * Dz);
}